// Round 12
// baseline (303.350 us; speedup 1.0000x reference)
//
#include <hip/hip_runtime.h>
#include <hip/hip_bf16.h>

#define HW    12288
#define Wimg  192
#define Himg  64
#define Wpad  194
#define Ppad  12804   // 66*194

// ---------------------------------------------------------------------------
// K1: deformable gather (unchanged from R11: register metadata, XCD swizzle,
// software-pipelined channel loop, launch_bounds(256,4)).
// ---------------------------------------------------------------------------
__global__ __launch_bounds__(256, 4) void k_deform(
    const float* __restrict__ x,     // 256 x HW
    const float* __restrict__ xr,    // HW
    const float* __restrict__ rout,  // 256 x 9
    float* __restrict__ y0)          // 256 x HW
{
    const int cblk = blockIdx.x;     // 0..7   (fastest -> XCD id)
    const int tile = blockIdx.y;     // 0..191
    const int pl   = threadIdx.x & 63;
    const int wv   = __builtin_amdgcn_readfirstlane(threadIdx.x >> 6);
    const int gp   = tile * 64 + pl;
    const int h = gp / Wimg, w = gp - h * Wimg;

    int   gi[6][3];
    float gw[6][3];
    const float off = 3.0f / (1.0f + expf(-xr[gp]));

    #pragma unroll
    for (int t = 0; t < 6; ++t) {
        const int xo = (t & 1) ? 1 : -1;
        const int yo = (t >> 1) - 1;
        float ov  = off * (float)xo;
        int   iv  = yo * Wpad;
        int   pre = (h + 1) * Wpad + (w + 1) + xo + iv;
        float after = (float)(pre + iv) + ov;
        int fl = (int)floorf(ov);
        int ce = (int)ceilf(ov);
        int av_f  = min(max(pre + fl + iv, 0), Ppad - 1);
        int av_f1 = min(max(av_f + xo,    0), Ppad - 1);
        int av_c  = min(max(pre + ce + iv, 0), Ppad - 1);
        int av_c1 = min(max(av_c + xo,    0), Ppad - 1);
        float wf  = fabsf(after - (float)av_f);
        float wf1 = fabsf((float)av_f1 - after);
        float wc1 = fabsf(after - (float)av_c1);
        float wc  = fabsf((float)av_c - after);
        float s1 = wf  * (1.0f / Wpad);
        float s2 = wc1 * (1.0f / Wpad);
        int   i4[4] = { av_f, av_f1, av_c1, av_c };
        float w4[4] = { s1 * wf, s1 * wf1, s2 * wc1, s2 * wc };
        int b = min(min(i4[0], i4[1]), min(i4[2], i4[3]));
        #pragma unroll
        for (int s = 0; s < 3; ++s) {
            float ws = 0.0f;
            #pragma unroll
            for (int j = 0; j < 4; ++j)
                ws += (i4[j] == b + s) ? w4[j] : 0.0f;
            int av = b + s;
            int r  = av / Wpad;
            int cc = av - r * Wpad;
            bool inb = (r >= 1) && (r <= Himg) && (cc >= 1) && (cc <= Wimg);
            gi[t][s] = inb ? ((r - 1) * Wimg + (cc - 1)) : 0;
            gw[t][s] = inb ? ws : 0.0f;
        }
    }

    const int c0 = cblk * 32 + wv * 8;
    float cur[18], nxt[18];
    {
        const float* xc = x + (size_t)c0 * HW;
        #pragma unroll
        for (int u = 0; u < 18; ++u)
            cur[u] = xc[gi[u / 3][u % 3]];
    }
    #pragma unroll
    for (int i = 0; i < 8; ++i) {
        if (i < 7) {
            const float* xn = x + (size_t)(c0 + i + 1) * HW;
            #pragma unroll
            for (int u = 0; u < 18; ++u)
                nxt[u] = xn[gi[u / 3][u % 3]];
        }
        const float* rc = rout + (c0 + i) * 9;
        float acc = 0.0f;
        #pragma unroll
        for (int t = 0; t < 6; ++t) {
            float part = gw[t][0] * cur[3 * t]
                       + gw[t][1] * cur[3 * t + 1]
                       + gw[t][2] * cur[3 * t + 2];
            const int k = 3 * (t >> 1) + ((t & 1) ? 2 : 0);
            acc += rc[k] * part;
        }
        y0[(size_t)(c0 + i) * HW + gp] = acc;
        #pragma unroll
        for (int u = 0; u < 18; ++u) cur[u] = nxt[u];
    }
}

// ---------------------------------------------------------------------------
// Pointwise GEMM, full-K, direct store + fused BN stats:
//   Z[128 x HW] = W[128 x CIN] * A[CIN x HW]
// Block = 32 px x 64 outs, grid (384 px-tiles, 2 o-blocks) = 768 blocks.
// px fastest + 384%8==0 -> both o-blocks of a px tile land on the SAME XCD
// (A-tile L2 reuse).  256 threads, each 2o x 4px.  32-deep LDS chunks, W
// transpose-staged (+4 pad).  Epilogue: per-channel (sum,sumsq) via width-8
// shuffle + 128 atomicAdds/block (98k total -- negligible).
// ---------------------------------------------------------------------------
template <int CIN>
__global__ __launch_bounds__(256) void k_pw(
    const float* __restrict__ A,     // CIN x HW
    const float* __restrict__ Wm,    // 128 x CIN (original layout)
    float* __restrict__ Z,           // 128 x HW
    float* __restrict__ psum)        // 128 x {sum,sumsq}, pre-zeroed
{
    __shared__ float s_a[32][32];    // [c_local][px]
    __shared__ float s_w[32][68];    // [c_local][o_local], +4 pad
    const int tid = threadIdx.x;
    const int tx  = tid & 7;         // px group (4 px)
    const int ty  = tid >> 3;        // o group (2 outs)
    const int px0 = blockIdx.x * 32;
    const int o0  = blockIdx.y * 64;

    float acc[2][4];
    #pragma unroll
    for (int i = 0; i < 2; ++i)
        #pragma unroll
        for (int j = 0; j < 4; ++j) acc[i][j] = 0.0f;

    const int ar = tid >> 5;         // A staging: rows ar+8i (i<4), col ac
    const int ac = tid & 31;
    const int wo = tid >> 5;         // W staging: o_local wo+8i (i<8), c = wl
    const int wl = tid & 31;

    for (int cb = 0; cb < CIN; cb += 32) {
        #pragma unroll
        for (int i = 0; i < 4; ++i)
            s_a[ar + 8 * i][ac] = A[(size_t)(cb + ar + 8 * i) * HW + px0 + ac];
        #pragma unroll
        for (int i = 0; i < 8; ++i)
            s_w[wl][wo + 8 * i] = Wm[(size_t)(o0 + wo + 8 * i) * CIN + cb + wl];
        __syncthreads();
        #pragma unroll
        for (int cc = 0; cc < 32; ++cc) {
            float4 a4 = *(const float4*)&s_a[cc][tx * 4];
            float2 w2 = *(const float2*)&s_w[cc][ty * 2];
            acc[0][0] += w2.x * a4.x; acc[0][1] += w2.x * a4.y;
            acc[0][2] += w2.x * a4.z; acc[0][3] += w2.x * a4.w;
            acc[1][0] += w2.y * a4.x; acc[1][1] += w2.y * a4.y;
            acc[1][2] += w2.y * a4.z; acc[1][3] += w2.y * a4.w;
        }
        __syncthreads();
    }

    #pragma unroll
    for (int i = 0; i < 2; ++i) {
        float4 v = make_float4(acc[i][0], acc[i][1], acc[i][2], acc[i][3]);
        *(float4*)&Z[(size_t)(o0 + ty * 2 + i) * HW + px0 + tx * 4] = v;
    }

    // fused BN partial stats: reduce the 8 tx-lanes (32 px) per channel
    #pragma unroll
    for (int i = 0; i < 2; ++i) {
        float s = acc[i][0] + acc[i][1] + acc[i][2] + acc[i][3];
        float q = acc[i][0] * acc[i][0] + acc[i][1] * acc[i][1]
                + acc[i][2] * acc[i][2] + acc[i][3] * acc[i][3];
        #pragma unroll
        for (int off = 4; off > 0; off >>= 1) {
            s += __shfl_down(s, off, 8);
            q += __shfl_down(q, off, 8);
        }
        if (tx == 0) {
            atomicAdd(&psum[2 * (o0 + ty * 2 + i)],     s);
            atomicAdd(&psum[2 * (o0 + ty * 2 + i) + 1], q);
        }
    }
}

// ---------------------------------------------------------------------------
// Fused BN(inline params)+LeakyReLU then depthwise 3x3 (zero pad 1).
// 4 px / thread, float4 store.  grid = 1536.
// ---------------------------------------------------------------------------
__global__ __launch_bounds__(256) void k_dw(
    const float* __restrict__ Z,
    const float* __restrict__ psum,  // 128 x {sum,sumsq}
    const float* __restrict__ g,
    const float* __restrict__ b,
    const float* __restrict__ dwgt,  // 128 x 9
    float4* __restrict__ D)
{
    const int t  = blockIdx.x * 256 + threadIdx.x;  // 0..393215
    const int c  = t / 3072;                        // HW/4 groups per channel
    const int gg = t - c * 3072;
    const int h  = gg / 48;                         // 192/4 = 48 groups/row
    const int w0 = (gg - h * 48) << 2;

    const float s   = psum[2 * c];
    const float q   = psum[2 * c + 1];
    const float mu  = s * (1.0f / HW);
    const float var = q * (1.0f / HW) - mu * mu;
    const float sc  = g[c] * rsqrtf(var + 1e-5f);
    const float sh  = b[c] - mu * sc;

    float wk[9];
    #pragma unroll
    for (int k = 0; k < 9; ++k) wk[k] = dwgt[c * 9 + k];

    const float* zc = Z + (size_t)c * HW;
    float v[3][6];
    #pragma unroll
    for (int ky = 0; ky < 3; ++ky) {
        const int hh  = h + ky - 1;
        const bool rin = (hh >= 0) && (hh < Himg);
        #pragma unroll
        for (int j = 0; j < 6; ++j) {
            const int ww = w0 - 1 + j;
            const bool in = rin && (ww >= 0) && (ww < Wimg);
            float z = in ? zc[hh * Wimg + ww] : 0.0f;
            float y = z * sc + sh;
            y = (y >= 0.0f) ? y : 0.01f * y;
            v[ky][j] = in ? y : 0.0f;
        }
    }

    float o[4];
    #pragma unroll
    for (int j = 0; j < 4; ++j) {
        float a = 0.0f;
        #pragma unroll
        for (int ky = 0; ky < 3; ++ky)
            #pragma unroll
            for (int kx = 0; kx < 3; ++kx)
                a += wk[ky * 3 + kx] * v[ky][j + kx];
        o[j] = a;
    }
    D[t] = make_float4(o[0], o[1], o[2], o[3]);
}

// ---------------------------------------------------------------------------
// Final BN(inline params)+LeakyReLU, float4.  grid = 1536.
// ---------------------------------------------------------------------------
__global__ __launch_bounds__(256) void k_final(
    const float4* __restrict__ Z,
    const float* __restrict__ psum,
    const float* __restrict__ g,
    const float* __restrict__ b,
    float4* __restrict__ out)
{
    const int f = blockIdx.x * 256 + threadIdx.x;   // 0..393215
    const int c = f / 3072;                          // HW/4 = 3072

    const float s   = psum[2 * c];
    const float q   = psum[2 * c + 1];
    const float mu  = s * (1.0f / HW);
    const float var = q * (1.0f / HW) - mu * mu;
    const float sc  = g[c] * rsqrtf(var + 1e-5f);
    const float sh  = b[c] - mu * sc;

    float4 z = Z[f];
    float4 v;
    v.x = z.x * sc + sh; v.x = (v.x >= 0.0f) ? v.x : 0.01f * v.x;
    v.y = z.y * sc + sh; v.y = (v.y >= 0.0f) ? v.y : 0.01f * v.y;
    v.z = z.z * sc + sh; v.z = (v.z >= 0.0f) ? v.z : 0.01f * v.z;
    v.w = z.w * sc + sh; v.w = (v.w >= 0.0f) ? v.w : 0.01f * v.w;
    out[f] = v;
}

// ---------------------------------------------------------------------------
extern "C" void kernel_launch(void* const* d_in, const int* in_sizes, int n_in,
                              void* d_out, int out_size, void* d_ws, size_t ws_size,
                              hipStream_t stream) {
    const float* x   = (const float*)d_in[0];
    const float* xr  = (const float*)d_in[1];
    const float* ro  = (const float*)d_in[2];
    const float* wr  = (const float*)d_in[3];
    const float* gr  = (const float*)d_in[4];
    const float* br  = (const float*)d_in[5];
    const float* dw1 = (const float*)d_in[6];
    const float* pw1 = (const float*)d_in[7];
    const float* g1  = (const float*)d_in[8];
    const float* b1  = (const float*)d_in[9];
    const float* dw2 = (const float*)d_in[10];
    const float* pw2 = (const float*)d_in[11];
    const float* g2  = (const float*)d_in[12];
    const float* b2  = (const float*)d_in[13];

    float* ws = (float*)d_ws;
    // A slot: 3,145,728 floats (y0; later z2 = lo, z3 = hi)
    // B slot: 1,572,864        (z1; later d2)
    // C slot: 1,572,864        (d1)
    float* A   = ws;
    float* B   = ws + 3145728;
    float* C   = ws + 4718592;
    float* y0  = A;
    float* z1  = B;
    float* d1  = C;
    float* z2  = A;                  // first half of A (y0 dead)
    float* d2  = B;                  // z1 dead
    float* z3  = A + 1572864;        // second half of A
    float* p1  = ws + 6291456;
    float* p2  = p1 + 256;
    float* p3  = p2 + 256;
    float* out = (float*)d_out;

    hipMemsetAsync(p1, 0, 768 * 4, stream);            // p1,p2,p3

    k_deform<<<dim3(8, 192), 256, 0, stream>>>(x, xr, ro, y0);
    k_pw<256><<<dim3(384, 2), 256, 0, stream>>>(y0, wr, z1, p1);
    k_dw<<<1536, 256, 0, stream>>>(z1, p1, gr, br, dw1, (float4*)d1);
    k_pw<128><<<dim3(384, 2), 256, 0, stream>>>(d1, pw1, z2, p2);
    k_dw<<<1536, 256, 0, stream>>>(z2, p2, g1, b1, dw2, (float4*)d2);
    k_pw<128><<<dim3(384, 2), 256, 0, stream>>>(d2, pw2, z3, p3);
    k_final<<<1536, 256, 0, stream>>>((const float4*)z3, p3, g2, b2, (float4*)out);
}

// Round 13
// 196.740 us; speedup vs baseline: 1.5419x; 1.5419x over previous
//
#include <hip/hip_runtime.h>
#include <hip/hip_bf16.h>

#define HW    12288
#define Wimg  192
#define Himg  64
#define Wpad  194
#define Ppad  12804   // 66*194

// ---------------------------------------------------------------------------
// K1: deformable gather (R11: register metadata, XCD swizzle, software-
// pipelined channel loop, launch_bounds(256,4)).
// ---------------------------------------------------------------------------
__global__ __launch_bounds__(256, 4) void k_deform(
    const float* __restrict__ x,     // 256 x HW
    const float* __restrict__ xr,    // HW
    const float* __restrict__ rout,  // 256 x 9
    float* __restrict__ y0)          // 256 x HW
{
    const int cblk = blockIdx.x;     // 0..7   (fastest -> XCD id)
    const int tile = blockIdx.y;     // 0..191
    const int pl   = threadIdx.x & 63;
    const int wv   = __builtin_amdgcn_readfirstlane(threadIdx.x >> 6);
    const int gp   = tile * 64 + pl;
    const int h = gp / Wimg, w = gp - h * Wimg;

    int   gi[6][3];
    float gw[6][3];
    const float off = 3.0f / (1.0f + expf(-xr[gp]));

    #pragma unroll
    for (int t = 0; t < 6; ++t) {
        const int xo = (t & 1) ? 1 : -1;
        const int yo = (t >> 1) - 1;
        float ov  = off * (float)xo;
        int   iv  = yo * Wpad;
        int   pre = (h + 1) * Wpad + (w + 1) + xo + iv;
        float after = (float)(pre + iv) + ov;
        int fl = (int)floorf(ov);
        int ce = (int)ceilf(ov);
        int av_f  = min(max(pre + fl + iv, 0), Ppad - 1);
        int av_f1 = min(max(av_f + xo,    0), Ppad - 1);
        int av_c  = min(max(pre + ce + iv, 0), Ppad - 1);
        int av_c1 = min(max(av_c + xo,    0), Ppad - 1);
        float wf  = fabsf(after - (float)av_f);
        float wf1 = fabsf((float)av_f1 - after);
        float wc1 = fabsf(after - (float)av_c1);
        float wc  = fabsf((float)av_c - after);
        float s1 = wf  * (1.0f / Wpad);
        float s2 = wc1 * (1.0f / Wpad);
        int   i4[4] = { av_f, av_f1, av_c1, av_c };
        float w4[4] = { s1 * wf, s1 * wf1, s2 * wc1, s2 * wc };
        int b = min(min(i4[0], i4[1]), min(i4[2], i4[3]));
        #pragma unroll
        for (int s = 0; s < 3; ++s) {
            float ws = 0.0f;
            #pragma unroll
            for (int j = 0; j < 4; ++j)
                ws += (i4[j] == b + s) ? w4[j] : 0.0f;
            int av = b + s;
            int r  = av / Wpad;
            int cc = av - r * Wpad;
            bool inb = (r >= 1) && (r <= Himg) && (cc >= 1) && (cc <= Wimg);
            gi[t][s] = inb ? ((r - 1) * Wimg + (cc - 1)) : 0;
            gw[t][s] = inb ? ws : 0.0f;
        }
    }

    const int c0 = cblk * 32 + wv * 8;
    float cur[18], nxt[18];
    {
        const float* xc = x + (size_t)c0 * HW;
        #pragma unroll
        for (int u = 0; u < 18; ++u)
            cur[u] = xc[gi[u / 3][u % 3]];
    }
    #pragma unroll
    for (int i = 0; i < 8; ++i) {
        if (i < 7) {
            const float* xn = x + (size_t)(c0 + i + 1) * HW;
            #pragma unroll
            for (int u = 0; u < 18; ++u)
                nxt[u] = xn[gi[u / 3][u % 3]];
        }
        const float* rc = rout + (c0 + i) * 9;
        float acc = 0.0f;
        #pragma unroll
        for (int t = 0; t < 6; ++t) {
            float part = gw[t][0] * cur[3 * t]
                       + gw[t][1] * cur[3 * t + 1]
                       + gw[t][2] * cur[3 * t + 2];
            const int k = 3 * (t >> 1) + ((t & 1) ? 2 : 0);
            acc += rc[k] * part;
        }
        y0[(size_t)(c0 + i) * HW + gp] = acc;
        #pragma unroll
        for (int u = 0; u < 18; ++u) cur[u] = nxt[u];
    }
}

// ---------------------------------------------------------------------------
// Pointwise GEMM, split-K into partial buffers (R8/R11-proven config):
//   Zp[z][128 x HW] = W[128, K-half z] * A[K-half z, HW]
// Block = 64 px x 64 outs, grid (192, 2, 2) = 768 blocks.  4x4 register
// tile, 32-deep LDS chunks, W transpose-staged (+4 pad), float4 stores.
// ---------------------------------------------------------------------------
template <int CIN>
__global__ __launch_bounds__(256) void k_pw(
    const float* __restrict__ A,     // CIN x HW
    const float* __restrict__ Wm,    // 128 x CIN (original layout)
    float* __restrict__ Zp0,         // partial for K-half 0
    float* __restrict__ Zp1)         // partial for K-half 1
{
    __shared__ float s_a[32][64];
    __shared__ float s_w[32][68];    // [c_local][o_local], +4 pad
    const int tid = threadIdx.x;
    const int tx  = tid & 15;        // px group (4 px)
    const int ty  = tid >> 4;        // o group (4 outs)
    const int px0 = blockIdx.x * 64;
    const int o0  = blockIdx.y * 64;
    const int KH  = CIN / 2;
    const int cb0 = blockIdx.z * KH;
    float* __restrict__ Zp = blockIdx.z ? Zp1 : Zp0;

    float acc[4][4];
    #pragma unroll
    for (int i = 0; i < 4; ++i)
        #pragma unroll
        for (int j = 0; j < 4; ++j) acc[i][j] = 0.0f;

    const int sr = tid >> 6;         // A staging row base (0..3), rows sr+4i
    const int sc = tid & 63;         // A staging col
    const int wo = tid >> 5;         // W staging: o_local base (0..7)
    const int wl = tid & 31;         // W staging: c_local

    for (int cb = cb0; cb < cb0 + KH; cb += 32) {
        #pragma unroll
        for (int i = 0; i < 8; ++i)
            s_a[sr + 4 * i][sc] = A[(size_t)(cb + sr + 4 * i) * HW + px0 + sc];
        #pragma unroll
        for (int i = 0; i < 8; ++i)
            s_w[wl][wo + 8 * i] = Wm[(size_t)(o0 + wo + 8 * i) * CIN + cb + wl];
        __syncthreads();
        #pragma unroll
        for (int cc = 0; cc < 32; ++cc) {
            float4 a4 = *(const float4*)&s_a[cc][tx * 4];
            float4 w4 = *(const float4*)&s_w[cc][ty * 4];
            acc[0][0] += w4.x * a4.x; acc[0][1] += w4.x * a4.y;
            acc[0][2] += w4.x * a4.z; acc[0][3] += w4.x * a4.w;
            acc[1][0] += w4.y * a4.x; acc[1][1] += w4.y * a4.y;
            acc[1][2] += w4.y * a4.z; acc[1][3] += w4.y * a4.w;
            acc[2][0] += w4.z * a4.x; acc[2][1] += w4.z * a4.y;
            acc[2][2] += w4.z * a4.z; acc[2][3] += w4.z * a4.w;
            acc[3][0] += w4.w * a4.x; acc[3][1] += w4.w * a4.y;
            acc[3][2] += w4.w * a4.z; acc[3][3] += w4.w * a4.w;
        }
        __syncthreads();
    }

    #pragma unroll
    for (int i = 0; i < 4; ++i) {
        float4 v = make_float4(acc[i][0], acc[i][1], acc[i][2], acc[i][3]);
        *(float4*)&Zp[(size_t)(o0 + ty * 4 + i) * HW + px0 + tx * 4] = v;
    }
}

// ---------------------------------------------------------------------------
// Combine split-K partials + BN stats (float4):  Z = Zp0 + Zp1.
// grid = (128 ch x 4 segments).
// ---------------------------------------------------------------------------
__global__ __launch_bounds__(256) void k_combine(
    const float* __restrict__ Zp0,
    const float* __restrict__ Zp1,
    float* __restrict__ Z,
    float* __restrict__ psum)        // 128 x {sum,sumsq}, pre-zeroed
{
    __shared__ float s_s[4], s_q[4];
    const int c   = blockIdx.x >> 2;
    const int seg = blockIdx.x & 3;
    const int tid = threadIdx.x;
    const size_t base = (size_t)c * HW + seg * 3072;
    const float4* a4 = (const float4*)(Zp0 + base);
    const float4* b4 = (const float4*)(Zp1 + base);
    float4*       z4 = (float4*)(Z + base);
    float s = 0.0f, q = 0.0f;
    #pragma unroll
    for (int i = 0; i < 3; ++i) {
        float4 a = a4[tid + i * 256];
        float4 b = b4[tid + i * 256];
        float4 v = make_float4(a.x + b.x, a.y + b.y, a.z + b.z, a.w + b.w);
        z4[tid + i * 256] = v;
        s += v.x + v.y + v.z + v.w;
        q += v.x * v.x + v.y * v.y + v.z * v.z + v.w * v.w;
    }
    #pragma unroll
    for (int off = 32; off > 0; off >>= 1) {
        s += __shfl_down(s, off, 64);
        q += __shfl_down(q, off, 64);
    }
    if ((tid & 63) == 0) { s_s[tid >> 6] = s; s_q[tid >> 6] = q; }
    __syncthreads();
    if (tid == 0) {
        s = s_s[0] + s_s[1] + s_s[2] + s_s[3];
        q = s_q[0] + s_q[1] + s_q[2] + s_q[3];
        atomicAdd(&psum[2 * c],     s);
        atomicAdd(&psum[2 * c + 1], q);
    }
}

// ---------------------------------------------------------------------------
// Fused BN(inline params from psum)+LeakyReLU then depthwise 3x3 (zero pad).
// 4 px / thread, float4 store.  grid = 1536.
// ---------------------------------------------------------------------------
__global__ __launch_bounds__(256) void k_dw(
    const float* __restrict__ Z,
    const float* __restrict__ psum,  // 128 x {sum,sumsq}
    const float* __restrict__ g,
    const float* __restrict__ b,
    const float* __restrict__ dwgt,  // 128 x 9
    float4* __restrict__ D)
{
    const int t  = blockIdx.x * 256 + threadIdx.x;  // 0..393215
    const int c  = t / 3072;                        // HW/4 groups per channel
    const int gg = t - c * 3072;
    const int h  = gg / 48;                         // 192/4 = 48 groups/row
    const int w0 = (gg - h * 48) << 2;

    const float s   = psum[2 * c];
    const float q   = psum[2 * c + 1];
    const float mu  = s * (1.0f / HW);
    const float var = q * (1.0f / HW) - mu * mu;
    const float sc  = g[c] * rsqrtf(var + 1e-5f);
    const float sh  = b[c] - mu * sc;

    float wk[9];
    #pragma unroll
    for (int k = 0; k < 9; ++k) wk[k] = dwgt[c * 9 + k];

    const float* zc = Z + (size_t)c * HW;
    float v[3][6];
    #pragma unroll
    for (int ky = 0; ky < 3; ++ky) {
        const int hh  = h + ky - 1;
        const bool rin = (hh >= 0) && (hh < Himg);
        #pragma unroll
        for (int j = 0; j < 6; ++j) {
            const int ww = w0 - 1 + j;
            const bool in = rin && (ww >= 0) && (ww < Wimg);
            float z = in ? zc[hh * Wimg + ww] : 0.0f;
            float y = z * sc + sh;
            y = (y >= 0.0f) ? y : 0.01f * y;
            v[ky][j] = in ? y : 0.0f;
        }
    }

    float o[4];
    #pragma unroll
    for (int j = 0; j < 4; ++j) {
        float a = 0.0f;
        #pragma unroll
        for (int ky = 0; ky < 3; ++ky)
            #pragma unroll
            for (int kx = 0; kx < 3; ++kx)
                a += wk[ky * 3 + kx] * v[ky][j + kx];
        o[j] = a;
    }
    D[t] = make_float4(o[0], o[1], o[2], o[3]);
}

// ---------------------------------------------------------------------------
// Final BN(inline params)+LeakyReLU, float4.  grid = 1536.
// ---------------------------------------------------------------------------
__global__ __launch_bounds__(256) void k_final(
    const float4* __restrict__ Z,
    const float* __restrict__ psum,
    const float* __restrict__ g,
    const float* __restrict__ b,
    float4* __restrict__ out)
{
    const int f = blockIdx.x * 256 + threadIdx.x;   // 0..393215
    const int c = f / 3072;                          // HW/4 = 3072

    const float s   = psum[2 * c];
    const float q   = psum[2 * c + 1];
    const float mu  = s * (1.0f / HW);
    const float var = q * (1.0f / HW) - mu * mu;
    const float sc  = g[c] * rsqrtf(var + 1e-5f);
    const float sh  = b[c] - mu * sc;

    float4 z = Z[f];
    float4 v;
    v.x = z.x * sc + sh; v.x = (v.x >= 0.0f) ? v.x : 0.01f * v.x;
    v.y = z.y * sc + sh; v.y = (v.y >= 0.0f) ? v.y : 0.01f * v.y;
    v.z = z.z * sc + sh; v.z = (v.z >= 0.0f) ? v.z : 0.01f * v.z;
    v.w = z.w * sc + sh; v.w = (v.w >= 0.0f) ? v.w : 0.01f * v.w;
    out[f] = v;
}

// ---------------------------------------------------------------------------
extern "C" void kernel_launch(void* const* d_in, const int* in_sizes, int n_in,
                              void* d_out, int out_size, void* d_ws, size_t ws_size,
                              hipStream_t stream) {
    const float* x   = (const float*)d_in[0];
    const float* xr  = (const float*)d_in[1];
    const float* ro  = (const float*)d_in[2];
    const float* wr  = (const float*)d_in[3];
    const float* gr  = (const float*)d_in[4];
    const float* br  = (const float*)d_in[5];
    const float* dw1 = (const float*)d_in[6];
    const float* pw1 = (const float*)d_in[7];
    const float* g1  = (const float*)d_in[8];
    const float* b1  = (const float*)d_in[9];
    const float* dw2 = (const float*)d_in[10];
    const float* pw2 = (const float*)d_in[11];
    const float* g2  = (const float*)d_in[12];
    const float* b2  = (const float*)d_in[13];

    float* ws = (float*)d_ws;
    // A: 3,145,728 floats  (y0; later zlo|zhi pairs)
    // B: 1,572,864         (Zp0)
    // C: 1,572,864         (Zp1)
    float* A   = ws;
    float* B   = ws + 3145728;
    float* C   = ws + 4718592;
    float* y0  = A;
    float* zlo = A;                  // combined Z slots
    float* zhi = A + 1572864;        // d slots
    float* p1  = ws + 6291456;
    float* p2  = p1 + 256;
    float* p3  = p2 + 256;
    float* out = (float*)d_out;

    hipMemsetAsync(p1, 0, 768 * 4, stream);            // p1,p2,p3

    k_deform<<<dim3(8, 192), 256, 0, stream>>>(x, xr, ro, y0);
    k_pw<256><<<dim3(192, 2, 2), 256, 0, stream>>>(y0, wr, B, C);
    k_combine<<<512, 256, 0, stream>>>(B, C, zlo, p1); // y0 dead -> z1 = zlo
    k_dw<<<1536, 256, 0, stream>>>(zlo, p1, gr, br, dw1, (float4*)zhi);
    k_pw<128><<<dim3(192, 2, 2), 256, 0, stream>>>(zhi, pw1, B, C);
    k_combine<<<512, 256, 0, stream>>>(B, C, zlo, p2);
    k_dw<<<1536, 256, 0, stream>>>(zlo, p2, g1, b1, dw2, (float4*)zhi);
    k_pw<128><<<dim3(192, 2, 2), 256, 0, stream>>>(zhi, pw2, B, C);
    k_combine<<<512, 256, 0, stream>>>(B, C, zlo, p3);
    k_final<<<1536, 256, 0, stream>>>((const float4*)zlo, p3, g2, b2, (float4*)out);
}

// Round 15
// 190.645 us; speedup vs baseline: 1.5912x; 1.0320x over previous
//
#include <hip/hip_runtime.h>
#include <hip/hip_bf16.h>

#define HW    12288
#define Wimg  192
#define Himg  64
#define Wpad  194
#define Ppad  12804   // 66*194

// ---------------------------------------------------------------------------
// K1: deformable gather via LDS-staged windows (FLAT-space staging).
// grid = (8 channel blocks, 192 tiles).  A tile = 64 consecutive columns of
// one image row.  All nonzero-weight gather targets of a pixel lie in 3
// flat-index windows [ (h+1+2yo)*Wpad + w0-4, +73 ] (the reference adds
// yo*Wpad twice).  Staging decomposes each FLAT index exactly like
// x_padded.reshape(P) -- including row-wrap targets (col -4 of row r ==
// col 190 of row r-1, a REAL pixel with nonzero weight; R14's 2D staging
// zeroed these -> absmax 2.99).  Gathers are conflict-free ds_reads.
// ---------------------------------------------------------------------------
__global__ __launch_bounds__(256, 4) void k_deform(
    const float* __restrict__ x,     // 256 x HW
    const float* __restrict__ xr,    // HW
    const float* __restrict__ rout,  // 256 x 9
    float* __restrict__ y0)          // 256 x HW
{
    __shared__ float s_x[32][240];   // 3 window rows x stride 80 (74 used)

    const int cblk = blockIdx.x;     // 0..7   (fastest -> XCD id)
    const int tile = blockIdx.y;     // 0..191
    const int tid  = threadIdx.x;
    const int pl   = tid & 63;
    const int wv   = __builtin_amdgcn_readfirstlane(tid >> 6);
    const int h    = tile / 3;
    const int w0   = (tile - h * 3) * 64;
    const int w    = w0 + pl;
    const int gp   = h * Wimg + w;   // == tile*64 + pl

    // ---- per-lane tap metadata: 6 x (window index, 3 merged weights) ----
    int   li[6];
    float gw[6][3];
    const float off = 3.0f / (1.0f + expf(-xr[gp]));

    #pragma unroll
    for (int t = 0; t < 6; ++t) {
        const int xo = (t & 1) ? 1 : -1;
        const int yo = (t >> 1) - 1;
        // replicate reference math exactly (flat space, double-iv quirk)
        float ov  = off * (float)xo;
        int   iv  = yo * Wpad;
        int   pre = (h + 1) * Wpad + (w + 1) + xo + iv;
        float after = (float)(pre + iv) + ov;
        int fl = (int)floorf(ov);
        int ce = (int)ceilf(ov);
        int av_f  = min(max(pre + fl + iv, 0), Ppad - 1);
        int av_f1 = min(max(av_f + xo,    0), Ppad - 1);
        int av_c  = min(max(pre + ce + iv, 0), Ppad - 1);
        int av_c1 = min(max(av_c + xo,    0), Ppad - 1);
        float wf  = fabsf(after - (float)av_f);
        float wf1 = fabsf((float)av_f1 - after);
        float wc1 = fabsf(after - (float)av_c1);
        float wc  = fabsf((float)av_c - after);
        float s1 = wf  * (1.0f / Wpad);
        float s2 = wc1 * (1.0f / Wpad);
        int   i4[4] = { av_f, av_f1, av_c1, av_c };
        float w4[4] = { s1 * wf, s1 * wf1, s2 * wc1, s2 * wc };
        int b = min(min(i4[0], i4[1]), min(i4[2], i4[3]));
        // window base for this tap's flat row
        const int base = (h + 1 + 2 * yo) * Wpad + w0 - 4;
        li[t] = (t >> 1) * 80 + min(max(b - base, 0), 71);
        #pragma unroll
        for (int s = 0; s < 3; ++s) {
            float ws = 0.0f;
            #pragma unroll
            for (int j = 0; j < 4; ++j)
                ws += (i4[j] == b + s) ? w4[j] : 0.0f;
            // zero weight for pad targets (true flat decomposition)
            int av = b + s;
            int r  = av / Wpad;
            int cc = av - r * Wpad;
            bool inb = (r >= 1) && (r <= Himg) && (cc >= 1) && (cc <= Wimg);
            gw[t][s] = inb ? ws : 0.0f;
        }
    }

    // ---- stage the 3x74 flat windows for the block's 32 channels ----
    const int jj = tid;              // active if < 222
    int  xoff = 0;
    bool valid = false;
    int  rr = 0, jcol = 0;
    if (jj < 222) {
        rr   = jj / 74;
        jcol = jj - rr * 74;
        const int flat = (h + 1 + 2 * (rr - 1)) * Wpad + w0 - 4 + jcol;
        if (flat >= 0 && flat < Ppad) {
            const int r = flat / Wpad;
            const int c = flat - r * Wpad;
            valid = (r >= 1) && (r <= Himg) && (c >= 1) && (c <= Wimg);
            xoff  = valid ? ((r - 1) * Wimg + (c - 1)) : 0;
        }
    }
    const float* xb = x + (size_t)(cblk * 32) * HW;
    for (int c = 0; c < 32; ++c) {
        if (jj < 222) {
            float v = valid ? xb[(size_t)c * HW + xoff] : 0.0f;
            s_x[c][rr * 80 + jcol] = v;
        }
    }
    __syncthreads();

    // ---- gather from LDS: 8 channels per wave ----
    // tap t -> rout column: xo=-1 -> 3*(yo+1), xo=+1 -> 3*(yo+1)+2
    const int c0l = wv * 8;
    #pragma unroll 2
    for (int i = 0; i < 8; ++i) {
        const int cl = c0l + i;
        const float* sxc = s_x[cl];
        const float* rc  = rout + (cblk * 32 + cl) * 9;
        float acc = 0.0f;
        #pragma unroll
        for (int t = 0; t < 6; ++t) {
            float part = gw[t][0] * sxc[li[t]]
                       + gw[t][1] * sxc[li[t] + 1]
                       + gw[t][2] * sxc[li[t] + 2];
            const int k = 3 * (t >> 1) + ((t & 1) ? 2 : 0);
            acc += rc[k] * part;
        }
        y0[(size_t)(cblk * 32 + cl) * HW + gp] = acc;
    }
}

// ---------------------------------------------------------------------------
// Pointwise GEMM, split-K into partial buffers (R8/R11-proven config):
//   Zp[z][128 x HW] = W[128, K-half z] * A[K-half z, HW]
// Block = 64 px x 64 outs, grid (192, 2, 2) = 768 blocks.  4x4 register
// tile, 32-deep LDS chunks, W transpose-staged (+4 pad), float4 stores.
// ---------------------------------------------------------------------------
template <int CIN>
__global__ __launch_bounds__(256) void k_pw(
    const float* __restrict__ A,     // CIN x HW
    const float* __restrict__ Wm,    // 128 x CIN (original layout)
    float* __restrict__ Zp0,         // partial for K-half 0
    float* __restrict__ Zp1)         // partial for K-half 1
{
    __shared__ float s_a[32][64];
    __shared__ float s_w[32][68];    // [c_local][o_local], +4 pad
    const int tid = threadIdx.x;
    const int tx  = tid & 15;        // px group (4 px)
    const int ty  = tid >> 4;        // o group (4 outs)
    const int px0 = blockIdx.x * 64;
    const int o0  = blockIdx.y * 64;
    const int KH  = CIN / 2;
    const int cb0 = blockIdx.z * KH;
    float* __restrict__ Zp = blockIdx.z ? Zp1 : Zp0;

    float acc[4][4];
    #pragma unroll
    for (int i = 0; i < 4; ++i)
        #pragma unroll
        for (int j = 0; j < 4; ++j) acc[i][j] = 0.0f;

    const int sr = tid >> 6;         // A staging row base (0..3), rows sr+4i
    const int sc = tid & 63;         // A staging col
    const int wo = tid >> 5;         // W staging: o_local base (0..7)
    const int wl = tid & 31;         // W staging: c_local

    for (int cb = cb0; cb < cb0 + KH; cb += 32) {
        #pragma unroll
        for (int i = 0; i < 8; ++i)
            s_a[sr + 4 * i][sc] = A[(size_t)(cb + sr + 4 * i) * HW + px0 + sc];
        #pragma unroll
        for (int i = 0; i < 8; ++i)
            s_w[wl][wo + 8 * i] = Wm[(size_t)(o0 + wo + 8 * i) * CIN + cb + wl];
        __syncthreads();
        #pragma unroll
        for (int cc = 0; cc < 32; ++cc) {
            float4 a4 = *(const float4*)&s_a[cc][tx * 4];
            float4 w4 = *(const float4*)&s_w[cc][ty * 4];
            acc[0][0] += w4.x * a4.x; acc[0][1] += w4.x * a4.y;
            acc[0][2] += w4.x * a4.z; acc[0][3] += w4.x * a4.w;
            acc[1][0] += w4.y * a4.x; acc[1][1] += w4.y * a4.y;
            acc[1][2] += w4.y * a4.z; acc[1][3] += w4.y * a4.w;
            acc[2][0] += w4.z * a4.x; acc[2][1] += w4.z * a4.y;
            acc[2][2] += w4.z * a4.z; acc[2][3] += w4.z * a4.w;
            acc[3][0] += w4.w * a4.x; acc[3][1] += w4.w * a4.y;
            acc[3][2] += w4.w * a4.z; acc[3][3] += w4.w * a4.w;
        }
        __syncthreads();
    }

    #pragma unroll
    for (int i = 0; i < 4; ++i) {
        float4 v = make_float4(acc[i][0], acc[i][1], acc[i][2], acc[i][3]);
        *(float4*)&Zp[(size_t)(o0 + ty * 4 + i) * HW + px0 + tx * 4] = v;
    }
}

// ---------------------------------------------------------------------------
// Combine split-K partials + BN stats (float4):  Z = Zp0 + Zp1.
// grid = (128 ch x 4 segments).
// ---------------------------------------------------------------------------
__global__ __launch_bounds__(256) void k_combine(
    const float* __restrict__ Zp0,
    const float* __restrict__ Zp1,
    float* __restrict__ Z,
    float* __restrict__ psum)        // 128 x {sum,sumsq}, pre-zeroed
{
    __shared__ float s_s[4], s_q[4];
    const int c   = blockIdx.x >> 2;
    const int seg = blockIdx.x & 3;
    const int tid = threadIdx.x;
    const size_t base = (size_t)c * HW + seg * 3072;
    const float4* a4 = (const float4*)(Zp0 + base);
    const float4* b4 = (const float4*)(Zp1 + base);
    float4*       z4 = (float4*)(Z + base);
    float s = 0.0f, q = 0.0f;
    #pragma unroll
    for (int i = 0; i < 3; ++i) {
        float4 a = a4[tid + i * 256];
        float4 b = b4[tid + i * 256];
        float4 v = make_float4(a.x + b.x, a.y + b.y, a.z + b.z, a.w + b.w);
        z4[tid + i * 256] = v;
        s += v.x + v.y + v.z + v.w;
        q += v.x * v.x + v.y * v.y + v.z * v.z + v.w * v.w;
    }
    #pragma unroll
    for (int off = 32; off > 0; off >>= 1) {
        s += __shfl_down(s, off, 64);
        q += __shfl_down(q, off, 64);
    }
    if ((tid & 63) == 0) { s_s[tid >> 6] = s; s_q[tid >> 6] = q; }
    __syncthreads();
    if (tid == 0) {
        s = s_s[0] + s_s[1] + s_s[2] + s_s[3];
        q = s_q[0] + s_q[1] + s_q[2] + s_q[3];
        atomicAdd(&psum[2 * c],     s);
        atomicAdd(&psum[2 * c + 1], q);
    }
}

// ---------------------------------------------------------------------------
// Fused BN(inline params from psum)+LeakyReLU then depthwise 3x3 (zero pad).
// 4 px / thread, float4 store.  grid = 1536.
// ---------------------------------------------------------------------------
__global__ __launch_bounds__(256) void k_dw(
    const float* __restrict__ Z,
    const float* __restrict__ psum,  // 128 x {sum,sumsq}
    const float* __restrict__ g,
    const float* __restrict__ b,
    const float* __restrict__ dwgt,  // 128 x 9
    float4* __restrict__ D)
{
    const int t  = blockIdx.x * 256 + threadIdx.x;  // 0..393215
    const int c  = t / 3072;                        // HW/4 groups per channel
    const int gg = t - c * 3072;
    const int h  = gg / 48;                         // 192/4 = 48 groups/row
    const int w0 = (gg - h * 48) << 2;

    const float s   = psum[2 * c];
    const float q   = psum[2 * c + 1];
    const float mu  = s * (1.0f / HW);
    const float var = q * (1.0f / HW) - mu * mu;
    const float sc  = g[c] * rsqrtf(var + 1e-5f);
    const float sh  = b[c] - mu * sc;

    float wk[9];
    #pragma unroll
    for (int k = 0; k < 9; ++k) wk[k] = dwgt[c * 9 + k];

    const float* zc = Z + (size_t)c * HW;
    float v[3][6];
    #pragma unroll
    for (int ky = 0; ky < 3; ++ky) {
        const int hh  = h + ky - 1;
        const bool rin = (hh >= 0) && (hh < Himg);
        #pragma unroll
        for (int j = 0; j < 6; ++j) {
            const int ww = w0 - 1 + j;
            const bool in = rin && (ww >= 0) && (ww < Wimg);
            float z = in ? zc[hh * Wimg + ww] : 0.0f;
            float y = z * sc + sh;
            y = (y >= 0.0f) ? y : 0.01f * y;
            v[ky][j] = in ? y : 0.0f;
        }
    }

    float o[4];
    #pragma unroll
    for (int j = 0; j < 4; ++j) {
        float a = 0.0f;
        #pragma unroll
        for (int ky = 0; ky < 3; ++ky)
            #pragma unroll
            for (int kx = 0; kx < 3; ++kx)
                a += wk[ky * 3 + kx] * v[ky][j + kx];
        o[j] = a;
    }
    D[t] = make_float4(o[0], o[1], o[2], o[3]);
}

// ---------------------------------------------------------------------------
// Final BN(inline params)+LeakyReLU, float4.  grid = 1536.
// ---------------------------------------------------------------------------
__global__ __launch_bounds__(256) void k_final(
    const float4* __restrict__ Z,
    const float* __restrict__ psum,
    const float* __restrict__ g,
    const float* __restrict__ b,
    float4* __restrict__ out)
{
    const int f = blockIdx.x * 256 + threadIdx.x;   // 0..393215
    const int c = f / 3072;                          // HW/4 = 3072

    const float s   = psum[2 * c];
    const float q   = psum[2 * c + 1];
    const float mu  = s * (1.0f / HW);
    const float var = q * (1.0f / HW) - mu * mu;
    const float sc  = g[c] * rsqrtf(var + 1e-5f);
    const float sh  = b[c] - mu * sc;

    float4 z = Z[f];
    float4 v;
    v.x = z.x * sc + sh; v.x = (v.x >= 0.0f) ? v.x : 0.01f * v.x;
    v.y = z.y * sc + sh; v.y = (v.y >= 0.0f) ? v.y : 0.01f * v.y;
    v.z = z.z * sc + sh; v.z = (v.z >= 0.0f) ? v.z : 0.01f * v.z;
    v.w = z.w * sc + sh; v.w = (v.w >= 0.0f) ? v.w : 0.01f * v.w;
    out[f] = v;
}

// ---------------------------------------------------------------------------
extern "C" void kernel_launch(void* const* d_in, const int* in_sizes, int n_in,
                              void* d_out, int out_size, void* d_ws, size_t ws_size,
                              hipStream_t stream) {
    const float* x   = (const float*)d_in[0];
    const float* xr  = (const float*)d_in[1];
    const float* ro  = (const float*)d_in[2];
    const float* wr  = (const float*)d_in[3];
    const float* gr  = (const float*)d_in[4];
    const float* br  = (const float*)d_in[5];
    const float* dw1 = (const float*)d_in[6];
    const float* pw1 = (const float*)d_in[7];
    const float* g1  = (const float*)d_in[8];
    const float* b1  = (const float*)d_in[9];
    const float* dw2 = (const float*)d_in[10];
    const float* pw2 = (const float*)d_in[11];
    const float* g2  = (const float*)d_in[12];
    const float* b2  = (const float*)d_in[13];

    float* ws = (float*)d_ws;
    // A: 3,145,728 floats  (y0; later zlo|zhi pairs)
    // B: 1,572,864         (Zp0)
    // C: 1,572,864         (Zp1)
    float* A   = ws;
    float* B   = ws + 3145728;
    float* C   = ws + 4718592;
    float* y0  = A;
    float* zlo = A;                  // combined Z slots
    float* zhi = A + 1572864;        // d slots
    float* p1  = ws + 6291456;
    float* p2  = p1 + 256;
    float* p3  = p2 + 256;
    float* out = (float*)d_out;

    hipMemsetAsync(p1, 0, 768 * 4, stream);            // p1,p2,p3

    k_deform<<<dim3(8, 192), 256, 0, stream>>>(x, xr, ro, y0);
    k_pw<256><<<dim3(192, 2, 2), 256, 0, stream>>>(y0, wr, B, C);
    k_combine<<<512, 256, 0, stream>>>(B, C, zlo, p1); // y0 dead -> z1 = zlo
    k_dw<<<1536, 256, 0, stream>>>(zlo, p1, gr, br, dw1, (float4*)zhi);
    k_pw<128><<<dim3(192, 2, 2), 256, 0, stream>>>(zhi, pw1, B, C);
    k_combine<<<512, 256, 0, stream>>>(B, C, zlo, p2);
    k_dw<<<1536, 256, 0, stream>>>(zlo, p2, g1, b1, dw2, (float4*)zhi);
    k_pw<128><<<dim3(192, 2, 2), 256, 0, stream>>>(zhi, pw2, B, C);
    k_combine<<<512, 256, 0, stream>>>(B, C, zlo, p3);
    k_final<<<1536, 256, 0, stream>>>((const float4*)zlo, p3, g2, b2, (float4*)out);
}

// Round 16
// 176.137 us; speedup vs baseline: 1.7222x; 1.0824x over previous
//
#include <hip/hip_runtime.h>
#include <hip/hip_bf16.h>

#define HW    12288
#define Wimg  192
#define Himg  64
#define Wpad  194
#define Ppad  12804   // 66*194

// bf16 <-> fp32 helpers (RNE), header-independent
static __device__ __forceinline__ unsigned short f2bf(float f) {
    union { float f; unsigned int u; } v; v.f = f;
    unsigned int r = v.u + 0x7fffu + ((v.u >> 16) & 1u);
    return (unsigned short)(r >> 16);
}
static __device__ __forceinline__ float bf2f(unsigned short h) {
    union { unsigned int u; float f; } v; v.u = ((unsigned int)h) << 16;
    return v.f;
}
static __device__ __forceinline__ float bflo(unsigned int u) {
    union { unsigned int u; float f; } v; v.u = u << 16; return v.f;
}
static __device__ __forceinline__ float bfhi(unsigned int u) {
    union { unsigned int u; float f; } v; v.u = u & 0xffff0000u; return v.f;
}

// ---------------------------------------------------------------------------
// K1: deformable gather via LDS-staged windows (flat-space staging, R15).
// Output y0 now bf16 (halves the write stream).
// ---------------------------------------------------------------------------
__global__ __launch_bounds__(256, 4) void k_deform(
    const float* __restrict__ x,     // 256 x HW
    const float* __restrict__ xr,    // HW
    const float* __restrict__ rout,  // 256 x 9
    unsigned short* __restrict__ y0) // 256 x HW (bf16)
{
    __shared__ float s_x[32][240];   // 3 window rows x stride 80 (74 used)

    const int cblk = blockIdx.x;     // 0..7   (fastest -> XCD id)
    const int tile = blockIdx.y;     // 0..191
    const int tid  = threadIdx.x;
    const int pl   = tid & 63;
    const int wv   = __builtin_amdgcn_readfirstlane(tid >> 6);
    const int h    = tile / 3;
    const int w0   = (tile - h * 3) * 64;
    const int w    = w0 + pl;
    const int gp   = h * Wimg + w;

    int   li[6];
    float gw[6][3];
    const float off = 3.0f / (1.0f + expf(-xr[gp]));

    #pragma unroll
    for (int t = 0; t < 6; ++t) {
        const int xo = (t & 1) ? 1 : -1;
        const int yo = (t >> 1) - 1;
        float ov  = off * (float)xo;
        int   iv  = yo * Wpad;
        int   pre = (h + 1) * Wpad + (w + 1) + xo + iv;
        float after = (float)(pre + iv) + ov;
        int fl = (int)floorf(ov);
        int ce = (int)ceilf(ov);
        int av_f  = min(max(pre + fl + iv, 0), Ppad - 1);
        int av_f1 = min(max(av_f + xo,    0), Ppad - 1);
        int av_c  = min(max(pre + ce + iv, 0), Ppad - 1);
        int av_c1 = min(max(av_c + xo,    0), Ppad - 1);
        float wf  = fabsf(after - (float)av_f);
        float wf1 = fabsf((float)av_f1 - after);
        float wc1 = fabsf(after - (float)av_c1);
        float wc  = fabsf((float)av_c - after);
        float s1 = wf  * (1.0f / Wpad);
        float s2 = wc1 * (1.0f / Wpad);
        int   i4[4] = { av_f, av_f1, av_c1, av_c };
        float w4[4] = { s1 * wf, s1 * wf1, s2 * wc1, s2 * wc };
        int b = min(min(i4[0], i4[1]), min(i4[2], i4[3]));
        const int base = (h + 1 + 2 * yo) * Wpad + w0 - 4;
        li[t] = (t >> 1) * 80 + min(max(b - base, 0), 71);
        #pragma unroll
        for (int s = 0; s < 3; ++s) {
            float ws = 0.0f;
            #pragma unroll
            for (int j = 0; j < 4; ++j)
                ws += (i4[j] == b + s) ? w4[j] : 0.0f;
            int av = b + s;
            int r  = av / Wpad;
            int cc = av - r * Wpad;
            bool inb = (r >= 1) && (r <= Himg) && (cc >= 1) && (cc <= Wimg);
            gw[t][s] = inb ? ws : 0.0f;
        }
    }

    // stage the 3x74 flat windows for the block's 32 channels
    const int jj = tid;
    int  xoff = 0;
    bool valid = false;
    int  rr = 0, jcol = 0;
    if (jj < 222) {
        rr   = jj / 74;
        jcol = jj - rr * 74;
        const int flat = (h + 1 + 2 * (rr - 1)) * Wpad + w0 - 4 + jcol;
        if (flat >= 0 && flat < Ppad) {
            const int r = flat / Wpad;
            const int c = flat - r * Wpad;
            valid = (r >= 1) && (r <= Himg) && (c >= 1) && (c <= Wimg);
            xoff  = valid ? ((r - 1) * Wimg + (c - 1)) : 0;
        }
    }
    const float* xb = x + (size_t)(cblk * 32) * HW;
    for (int c = 0; c < 32; ++c) {
        if (jj < 222) {
            float v = valid ? xb[(size_t)c * HW + xoff] : 0.0f;
            s_x[c][rr * 80 + jcol] = v;
        }
    }
    __syncthreads();

    const int c0l = wv * 8;
    #pragma unroll 2
    for (int i = 0; i < 8; ++i) {
        const int cl = c0l + i;
        const float* sxc = s_x[cl];
        const float* rc  = rout + (cblk * 32 + cl) * 9;
        float acc = 0.0f;
        #pragma unroll
        for (int t = 0; t < 6; ++t) {
            float part = gw[t][0] * sxc[li[t]]
                       + gw[t][1] * sxc[li[t] + 1]
                       + gw[t][2] * sxc[li[t] + 2];
            const int k = 3 * (t >> 1) + ((t & 1) ? 2 : 0);
            acc += rc[k] * part;
        }
        y0[(size_t)(cblk * 32 + cl) * HW + gp] = f2bf(acc);
    }
}

// ---------------------------------------------------------------------------
// Pointwise GEMM, split-K, bf16 A / bf16 partial outputs:
//   Zp[z] = W[128, K-half z] * A[K-half z, HW]
// Block = 64 px x 64 outs, grid (192, 2, 2).  A-chunk staged with ONE
// 16B (8 x bf16) load per thread per chunk (was 8 x 4B).  fp32 math in LDS
// and registers; stores packed ushort4 (4 x bf16).
// ---------------------------------------------------------------------------
template <int CIN>
__global__ __launch_bounds__(256) void k_pw(
    const unsigned short* __restrict__ A,   // CIN x HW (bf16)
    const float* __restrict__ Wm,           // 128 x CIN (fp32)
    unsigned short* __restrict__ Zp0,       // partial K-half 0 (bf16)
    unsigned short* __restrict__ Zp1)       // partial K-half 1 (bf16)
{
    __shared__ float s_a[32][64];
    __shared__ float s_w[32][68];    // +4 pad
    const int tid = threadIdx.x;
    const int tx  = tid & 15;        // px group (4 px)
    const int ty  = tid >> 4;        // o group (4 outs)
    const int px0 = blockIdx.x * 64;
    const int o0  = blockIdx.y * 64;
    const int KH  = CIN / 2;
    const int cb0 = blockIdx.z * KH;
    unsigned short* __restrict__ Zp = blockIdx.z ? Zp1 : Zp0;

    float acc[4][4];
    #pragma unroll
    for (int i = 0; i < 4; ++i)
        #pragma unroll
        for (int j = 0; j < 4; ++j) acc[i][j] = 0.0f;

    const int arow = tid >> 3;       // A staging: one row per thread (0..31)
    const int acg  = tid & 7;        // col group: 8 bf16
    const int wo = tid >> 5;         // W staging: o_local base (0..7)
    const int wl = tid & 31;         // W staging: c_local

    for (int cb = cb0; cb < cb0 + KH; cb += 32) {
        {
            const uint4* ap = (const uint4*)(A + (size_t)(cb + arow) * HW + px0);
            uint4 u = ap[acg];
            float4 lo = make_float4(bflo(u.x), bfhi(u.x), bflo(u.y), bfhi(u.y));
            float4 hi = make_float4(bflo(u.z), bfhi(u.z), bflo(u.w), bfhi(u.w));
            *(float4*)&s_a[arow][acg * 8]     = lo;
            *(float4*)&s_a[arow][acg * 8 + 4] = hi;
        }
        #pragma unroll
        for (int i = 0; i < 8; ++i)
            s_w[wl][wo + 8 * i] = Wm[(size_t)(o0 + wo + 8 * i) * CIN + cb + wl];
        __syncthreads();
        #pragma unroll
        for (int cc = 0; cc < 32; ++cc) {
            float4 a4 = *(const float4*)&s_a[cc][tx * 4];
            float4 w4 = *(const float4*)&s_w[cc][ty * 4];
            acc[0][0] += w4.x * a4.x; acc[0][1] += w4.x * a4.y;
            acc[0][2] += w4.x * a4.z; acc[0][3] += w4.x * a4.w;
            acc[1][0] += w4.y * a4.x; acc[1][1] += w4.y * a4.y;
            acc[1][2] += w4.y * a4.z; acc[1][3] += w4.y * a4.w;
            acc[2][0] += w4.z * a4.x; acc[2][1] += w4.z * a4.y;
            acc[2][2] += w4.z * a4.z; acc[2][3] += w4.z * a4.w;
            acc[3][0] += w4.w * a4.x; acc[3][1] += w4.w * a4.y;
            acc[3][2] += w4.w * a4.z; acc[3][3] += w4.w * a4.w;
        }
        __syncthreads();
    }

    #pragma unroll
    for (int i = 0; i < 4; ++i) {
        ushort4 v;
        v.x = f2bf(acc[i][0]); v.y = f2bf(acc[i][1]);
        v.z = f2bf(acc[i][2]); v.w = f2bf(acc[i][3]);
        *(ushort4*)&Zp[(size_t)(o0 + ty * 4 + i) * HW + px0 + tx * 4] = v;
    }
}

// ---------------------------------------------------------------------------
// Combine split-K partials + BN stats:  Z = Zp0 + Zp1 (bf16 in/out, fp32
// stats).  grid = (128 ch x 4 segments).
// ---------------------------------------------------------------------------
__global__ __launch_bounds__(256) void k_combine(
    const unsigned short* __restrict__ Zp0,
    const unsigned short* __restrict__ Zp1,
    unsigned short* __restrict__ Z,
    float* __restrict__ psum)        // 128 x {sum,sumsq}, pre-zeroed
{
    __shared__ float s_s[4], s_q[4];
    const int c   = blockIdx.x >> 2;
    const int seg = blockIdx.x & 3;
    const int tid = threadIdx.x;
    const size_t base = (size_t)c * HW + seg * 3072;
    const uint2* a4 = (const uint2*)(Zp0 + base);   // 4 bf16 / 8B
    const uint2* b4 = (const uint2*)(Zp1 + base);
    ushort4*     z4 = (ushort4*)(Z + base);
    float s = 0.0f, q = 0.0f;
    #pragma unroll
    for (int i = 0; i < 3; ++i) {
        uint2 a = a4[tid + i * 256];
        uint2 b = b4[tid + i * 256];
        float v0 = bflo(a.x) + bflo(b.x);
        float v1 = bfhi(a.x) + bfhi(b.x);
        float v2 = bflo(a.y) + bflo(b.y);
        float v3 = bfhi(a.y) + bfhi(b.y);
        ushort4 zz; zz.x = f2bf(v0); zz.y = f2bf(v1);
        zz.z = f2bf(v2); zz.w = f2bf(v3);
        z4[tid + i * 256] = zz;
        s += v0 + v1 + v2 + v3;
        q += v0 * v0 + v1 * v1 + v2 * v2 + v3 * v3;
    }
    #pragma unroll
    for (int off = 32; off > 0; off >>= 1) {
        s += __shfl_down(s, off, 64);
        q += __shfl_down(q, off, 64);
    }
    if ((tid & 63) == 0) { s_s[tid >> 6] = s; s_q[tid >> 6] = q; }
    __syncthreads();
    if (tid == 0) {
        s = s_s[0] + s_s[1] + s_s[2] + s_s[3];
        q = s_q[0] + s_q[1] + s_q[2] + s_q[3];
        atomicAdd(&psum[2 * c],     s);
        atomicAdd(&psum[2 * c + 1], q);
    }
}

// ---------------------------------------------------------------------------
// Fused BN(inline params)+LeakyReLU then depthwise 3x3 (zero pad).
// 4 px / thread; bf16 in/out.  grid = 1536.
// ---------------------------------------------------------------------------
__global__ __launch_bounds__(256) void k_dw(
    const unsigned short* __restrict__ Z,
    const float* __restrict__ psum,  // 128 x {sum,sumsq}
    const float* __restrict__ g,
    const float* __restrict__ b,
    const float* __restrict__ dwgt,  // 128 x 9
    ushort4* __restrict__ D)
{
    const int t  = blockIdx.x * 256 + threadIdx.x;  // 0..393215
    const int c  = t / 3072;
    const int gg = t - c * 3072;
    const int h  = gg / 48;
    const int w0 = (gg - h * 48) << 2;

    const float s   = psum[2 * c];
    const float q   = psum[2 * c + 1];
    const float mu  = s * (1.0f / HW);
    const float var = q * (1.0f / HW) - mu * mu;
    const float sc  = g[c] * rsqrtf(var + 1e-5f);
    const float sh  = b[c] - mu * sc;

    float wk[9];
    #pragma unroll
    for (int k = 0; k < 9; ++k) wk[k] = dwgt[c * 9 + k];

    const unsigned short* zc = Z + (size_t)c * HW;
    float v[3][6];
    #pragma unroll
    for (int ky = 0; ky < 3; ++ky) {
        const int hh  = h + ky - 1;
        const bool rin = (hh >= 0) && (hh < Himg);
        #pragma unroll
        for (int j = 0; j < 6; ++j) {
            const int ww = w0 - 1 + j;
            const bool in = rin && (ww >= 0) && (ww < Wimg);
            float z = in ? bf2f(zc[hh * Wimg + ww]) : 0.0f;
            float y = z * sc + sh;
            y = (y >= 0.0f) ? y : 0.01f * y;
            v[ky][j] = in ? y : 0.0f;
        }
    }

    ushort4 o;
    float oo[4];
    #pragma unroll
    for (int j = 0; j < 4; ++j) {
        float a = 0.0f;
        #pragma unroll
        for (int ky = 0; ky < 3; ++ky)
            #pragma unroll
            for (int kx = 0; kx < 3; ++kx)
                a += wk[ky * 3 + kx] * v[ky][j + kx];
        oo[j] = a;
    }
    o.x = f2bf(oo[0]); o.y = f2bf(oo[1]); o.z = f2bf(oo[2]); o.w = f2bf(oo[3]);
    D[t] = o;
}

// ---------------------------------------------------------------------------
// Final BN(inline params)+LeakyReLU: bf16 in, fp32 out.  grid = 1536.
// ---------------------------------------------------------------------------
__global__ __launch_bounds__(256) void k_final(
    const unsigned short* __restrict__ Z,
    const float* __restrict__ psum,
    const float* __restrict__ g,
    const float* __restrict__ b,
    float4* __restrict__ out)
{
    const int f = blockIdx.x * 256 + threadIdx.x;   // 0..393215
    const int c = f / 3072;

    const float s   = psum[2 * c];
    const float q   = psum[2 * c + 1];
    const float mu  = s * (1.0f / HW);
    const float var = q * (1.0f / HW) - mu * mu;
    const float sc  = g[c] * rsqrtf(var + 1e-5f);
    const float sh  = b[c] - mu * sc;

    uint2 zz = ((const uint2*)Z)[f];
    float4 v;
    v.x = bflo(zz.x) * sc + sh; v.x = (v.x >= 0.0f) ? v.x : 0.01f * v.x;
    v.y = bfhi(zz.x) * sc + sh; v.y = (v.y >= 0.0f) ? v.y : 0.01f * v.y;
    v.z = bflo(zz.y) * sc + sh; v.z = (v.z >= 0.0f) ? v.z : 0.01f * v.z;
    v.w = bfhi(zz.y) * sc + sh; v.w = (v.w >= 0.0f) ? v.w : 0.01f * v.w;
    out[f] = v;
}

// ---------------------------------------------------------------------------
extern "C" void kernel_launch(void* const* d_in, const int* in_sizes, int n_in,
                              void* d_out, int out_size, void* d_ws, size_t ws_size,
                              hipStream_t stream) {
    const float* x   = (const float*)d_in[0];
    const float* xr  = (const float*)d_in[1];
    const float* ro  = (const float*)d_in[2];
    const float* wr  = (const float*)d_in[3];
    const float* gr  = (const float*)d_in[4];
    const float* br  = (const float*)d_in[5];
    const float* dw1 = (const float*)d_in[6];
    const float* pw1 = (const float*)d_in[7];
    const float* g1  = (const float*)d_in[8];
    const float* b1  = (const float*)d_in[9];
    const float* dw2 = (const float*)d_in[10];
    const float* pw2 = (const float*)d_in[11];
    const float* g2  = (const float*)d_in[12];
    const float* b2  = (const float*)d_in[13];

    unsigned short* WS = (unsigned short*)d_ws;
    // bf16 buffers (element offsets); total footprint identical to R15:
    //   [0 .. 3145728)        y0  (later zlo = [0..1572864), zhi = [1572864..))
    //   [6291456 .. 7864320)  Zp0
    //   [9437184 .. 11010048) Zp1
    //   float params at byte 25165824
    unsigned short* y0  = WS;
    unsigned short* zlo = WS;
    unsigned short* zhi = WS + 1572864;
    unsigned short* B   = WS + 6291456;
    unsigned short* C   = WS + 9437184;
    float* p1 = (float*)(WS + 12582912);
    float* p2 = p1 + 256;
    float* p3 = p2 + 256;
    float* out = (float*)d_out;

    hipMemsetAsync(p1, 0, 768 * 4, stream);            // p1,p2,p3

    k_deform<<<dim3(8, 192), 256, 0, stream>>>(x, xr, ro, y0);
    k_pw<256><<<dim3(192, 2, 2), 256, 0, stream>>>(y0, wr, B, C);
    k_combine<<<512, 256, 0, stream>>>(B, C, zlo, p1); // y0 dead -> z1 = zlo
    k_dw<<<1536, 256, 0, stream>>>(zlo, p1, gr, br, dw1, (ushort4*)zhi);
    k_pw<128><<<dim3(192, 2, 2), 256, 0, stream>>>(zhi, pw1, B, C);
    k_combine<<<512, 256, 0, stream>>>(B, C, zlo, p2);
    k_dw<<<1536, 256, 0, stream>>>(zlo, p2, g1, b1, dw2, (ushort4*)zhi);
    k_pw<128><<<dim3(192, 2, 2), 256, 0, stream>>>(zhi, pw2, B, C);
    k_combine<<<512, 256, 0, stream>>>(B, C, zlo, p3);
    k_final<<<1536, 256, 0, stream>>>(zlo, p3, g2, b2, (float4*)out);
}